// Round 7
// baseline (12408.389 us; speedup 1.0000x reference)
//
#include <hip/hip_runtime.h>

typedef _Float16 f16;
typedef _Float16 f16x2 __attribute__((ext_vector_type(2)));
typedef _Float16 f16x4 __attribute__((ext_vector_type(4)));
typedef _Float16 f16x8 __attribute__((ext_vector_type(8)));
typedef float    f32x4 __attribute__((ext_vector_type(4)));

#define NSTEP 2048
#define HID   512
#define BATCH 32
#define SEQL  2048

// v_dot2_f32_f16: 2 f16 MACs, f32 accumulate.
#if __has_builtin(__builtin_amdgcn_fdot2)
#define FDOT2(a, b, c) __builtin_amdgcn_fdot2((a), (b), (c), false)
#else
static __device__ __forceinline__ float FDOT2(f16x2 a, f16x2 b, float c) {
    return c + (float)a[0] * (float)b[0] + (float)a[1] * (float)b[1];
}
#endif

// 8 f16 MACs = 4 fdot2; literal pair indices (shufflevector needs ICE).
// Each f16x2 pair is a natural VGPR subregister of the f16x8 (regs 0..3).
#define RNN_DOT8(AV, W, S)                                                  \
    do {                                                                    \
        S = FDOT2(__builtin_shufflevector(AV, AV, 0, 1),                    \
                  __builtin_shufflevector(W, W, 0, 1), S);                  \
        S = FDOT2(__builtin_shufflevector(AV, AV, 2, 3),                    \
                  __builtin_shufflevector(W, W, 2, 3), S);                  \
        S = FDOT2(__builtin_shufflevector(AV, AV, 4, 5),                    \
                  __builtin_shufflevector(W, W, 4, 5), S);                  \
        S = FDOT2(__builtin_shufflevector(AV, AV, 6, 7),                    \
                  __builtin_shufflevector(W, W, 6, 7), S);                  \
    } while (0)

// ---------------------------------------------------------------------------
// Phase 1: xproj[m][n] = sum_k x[m][k] * Wxh[n][k] + (bxh+bhh+bh)[n], f16 out
// M=65536, N=512, K=512.  Block: 64 rows x 512 cols, 256 threads (4 waves).
// ---------------------------------------------------------------------------
#define P1_AS 40   // padded lds stride (f16) to spread banks; 80B = 16B-aligned

__global__ __launch_bounds__(256, 2) void xproj_kernel(
    const float* __restrict__ x, const float* __restrict__ Wxh,
    const float* __restrict__ bxh, const float* __restrict__ bhh,
    const float* __restrict__ bh, f16* __restrict__ xp)
{
    __shared__ __align__(16) f16 As[64 * P1_AS];
    __shared__ __align__(16) f16 Bs[512 * P1_AS];

    const int t = threadIdx.x;
    const int wave = t >> 6, lane = t & 63;
    const size_t mbase = (size_t)blockIdx.x * 64;

    f32x4 acc[4][8];
#pragma unroll
    for (int i = 0; i < 4; i++)
#pragma unroll
        for (int j = 0; j < 8; j++) acc[i][j] = (f32x4){0.f, 0.f, 0.f, 0.f};

    const int r_st = t >> 2;          // 0..63
    const int koff = (t & 3) * 8;     // 0,8,16,24

    for (int k0 = 0; k0 < 512; k0 += 32) {
        __syncthreads();
        // stage A: 64 rows x 32 k (f32 -> f16)
        {
            const float* src = x + (mbase + r_st) * 512 + k0 + koff;
            float4 a0 = *(const float4*)src;
            float4 a1 = *(const float4*)(src + 4);
            f16x8 h;
            h[0] = (f16)a0.x; h[1] = (f16)a0.y; h[2] = (f16)a0.z; h[3] = (f16)a0.w;
            h[4] = (f16)a1.x; h[5] = (f16)a1.y; h[6] = (f16)a1.z; h[7] = (f16)a1.w;
            *(f16x8*)&As[r_st * P1_AS + koff] = h;
        }
        // stage B: 512 rows(n) x 32 k, 8 passes
#pragma unroll
        for (int i = 0; i < 8; i++) {
            int n = r_st + i * 64;
            const float* src = Wxh + (size_t)n * 512 + k0 + koff;
            float4 b0 = *(const float4*)src;
            float4 b1 = *(const float4*)(src + 4);
            f16x8 h;
            h[0] = (f16)b0.x; h[1] = (f16)b0.y; h[2] = (f16)b0.z; h[3] = (f16)b0.w;
            h[4] = (f16)b1.x; h[5] = (f16)b1.y; h[6] = (f16)b1.z; h[7] = (f16)b1.w;
            *(f16x8*)&Bs[n * P1_AS + koff] = h;
        }
        __syncthreads();

        // A frags: row = rt*16 + (lane&15), k = (lane>>4)*8 + j
        f16x8 af[4];
#pragma unroll
        for (int rt = 0; rt < 4; rt++)
            af[rt] = *(const f16x8*)&As[(rt * 16 + (lane & 15)) * P1_AS + (lane >> 4) * 8];
#pragma unroll
        for (int ct = 0; ct < 8; ct++) {
            f16x8 bf = *(const f16x8*)&Bs[((wave * 8 + ct) * 16 + (lane & 15)) * P1_AS + (lane >> 4) * 8];
#pragma unroll
            for (int rt = 0; rt < 4; rt++)
                acc[rt][ct] = __builtin_amdgcn_mfma_f32_16x16x32_f16(af[rt], bf, acc[rt][ct], 0, 0, 0);
        }
    }

    // epilogue: D col = lane&15, row = (lane>>4)*4 + r
#pragma unroll
    for (int ct = 0; ct < 8; ct++) {
        int n = wave * 128 + ct * 16 + (lane & 15);
        float bias = bxh[n] + bhh[n] + bh[n];
#pragma unroll
        for (int rt = 0; rt < 4; rt++) {
#pragma unroll
            for (int r = 0; r < 4; r++) {
                size_t m = mbase + rt * 16 + (lane >> 4) * 4 + r;
                xp[m * 512 + n] = (f16)(acc[rt][ct][r] + bias);
            }
        }
    }
}

// ---------------------------------------------------------------------------
// Phase 2: recurrence — ALL-VALU, 1024 threads (16 waves, 4/SIMD) per batch.
//
// r4-r6 lesson: hybrid MFMA/VALU at 512 threads needs ~256 weight regs/thread
// -> allocator caps at 128 and spills (r6 WRITE_SIZE 10 MB = scratch).
// At 1024 threads weights are 128 regs/thread (~200 total) — safe.
// Pure-VALU floor: 512x512 MAC / (256 MAC/cyc/CU fdot2) = 1024 cyc/step,
// vs r0's MFMA-redundant floor of 2483 cyc/step.
//
// Lane mapping: e = l&7 -> 4 consecutive cols c0 = w*32+e*4; q = l>>3 ->
// 64-elem k-chunk.  h stored PERMUTED in LDS at 16B granularity
// (idx = j*64 + q*8 + e, for h[q*64+j*8+e]) so the 8 ds_read_b128/step are
// conflict-free: 8 distinct 16B addrs cover all 32 banks, broadcast within
// 8-lane groups.  Col reduce = 3 shfl_xor over the q bits (8,16,32).
// ---------------------------------------------------------------------------
#define HPERM(c) ((((c) >> 3) & 7) * 64 + ((c) >> 6) * 8 + ((c) & 7))

__global__ __launch_bounds__(1024, 1) void rnn_kernel(
    const float* __restrict__ Whh, const f16* __restrict__ xp,
    f16* __restrict__ hfin)
{
    __shared__ __align__(16) f16 hls[2][HID];   // permuted h, double-buffered

    const int t = threadIdx.x;
    const int w = t >> 6, l = t & 63;
    const int b = blockIdx.x;
    const int e = l & 7;                 // col group within wave
    const int q = l >> 3;                // k-chunk 0..7
    const int c0 = w * 32 + e * 4;       // 4 consecutive output cols

    // ---- weights (one-time): wt[m][j] = Whh[c0+m][q*64 + j*8 .. +7] ----
    f16x8 wt[4][8];                      // 128 VGPRs, static-indexed
#pragma unroll
    for (int m = 0; m < 4; m++) {
        const float* wrow = Whh + (size_t)(c0 + m) * 512 + q * 64;
#pragma unroll
        for (int j = 0; j < 8; j++) {
            float4 w0 = *(const float4*)(wrow + j * 8);
            float4 w1 = *(const float4*)(wrow + j * 8 + 4);
            f16x8 h;
            h[0] = (f16)w0.x; h[1] = (f16)w0.y; h[2] = (f16)w0.z; h[3] = (f16)w0.w;
            h[4] = (f16)w1.x; h[5] = (f16)w1.y; h[6] = (f16)w1.z; h[7] = (f16)w1.w;
            wt[m][j] = h;
        }
    }

    if (t < HID) hls[0][t] = (f16)0.f;   // h0 = 0 (permutation of 0 is 0)
    __syncthreads();

    const size_t xbase = (size_t)b * SEQL * 512 + c0;
    // permuted write index for this thread's 4 cols (c0 aligned to 4)
    const int widx = HPERM(c0);

    // dist-1 prefetch, cvt at load (r0-proven pattern)
    float4 xv;
    {
        f16x4 xr = *(const f16x4*)&xp[xbase];
        xv.x = (float)xr[0]; xv.y = (float)xr[1]; xv.z = (float)xr[2]; xv.w = (float)xr[3];
    }

    for (int s = 0; s < NSTEP; s++) {
        const f16* cur = hls[s & 1];
        f16*       nxt = hls[(s & 1) ^ 1];
        int sn = (s + 1 < NSTEP) ? s + 1 : s;
        float4 xvn;
        {
            f16x4 xr = *(const f16x4*)&xp[xbase + (size_t)sn * 512];
            xvn.x = (float)xr[0]; xvn.y = (float)xr[1]; xvn.z = (float)xr[2]; xvn.w = (float)xr[3];
        }

        // h chunk q, 8 x conflict-free broadcast ds_read_b128
        f16x8 av[8];
#pragma unroll
        for (int j = 0; j < 8; j++)
            av[j] = *(const f16x8*)&cur[j * 64 + q * 8];

        float a0 = 0.f, a1 = 0.f, a2 = 0.f, a3 = 0.f;
#pragma unroll
        for (int j = 0; j < 8; j++) {
            RNN_DOT8(av[j], wt[0][j], a0);
            RNN_DOT8(av[j], wt[1][j], a1);
            RNN_DOT8(av[j], wt[2][j], a2);
            RNN_DOT8(av[j], wt[3][j], a3);
        }
        // reduce across k-chunks (lane bits 3,4,5); butterfly -> all lanes hold sums
        a0 += __shfl_xor(a0, 8, 64); a0 += __shfl_xor(a0, 16, 64); a0 += __shfl_xor(a0, 32, 64);
        a1 += __shfl_xor(a1, 8, 64); a1 += __shfl_xor(a1, 16, 64); a1 += __shfl_xor(a1, 32, 64);
        a2 += __shfl_xor(a2, 8, 64); a2 += __shfl_xor(a2, 16, 64); a2 += __shfl_xor(a2, 32, 64);
        a3 += __shfl_xor(a3, 8, 64); a3 += __shfl_xor(a3, 16, 64); a3 += __shfl_xor(a3, 32, 64);

        // tanh(v) = 1 - 2/(exp(2v)+1)  (saturates correctly, no NaN)
        float v0 = a0 + xv.x, v1 = a1 + xv.y, v2 = a2 + xv.z, v3 = a3 + xv.w;
        v0 = 1.f - 2.f / (__expf(2.f * v0) + 1.f);
        v1 = 1.f - 2.f / (__expf(2.f * v1) + 1.f);
        v2 = 1.f - 2.f / (__expf(2.f * v2) + 1.f);
        v3 = 1.f - 2.f / (__expf(2.f * v3) + 1.f);

        if (q == 0) {                    // one writer group per col set
            f16x4 hv;
            hv[0] = (f16)v0; hv[1] = (f16)v1; hv[2] = (f16)v2; hv[3] = (f16)v3;
            *(f16x4*)&nxt[widx] = hv;    // 8B-aligned permuted write
        }
        xv = xvn;
        __syncthreads();
    }
    // NSTEP even -> final h sits in hls[0] (permuted); un-permute on store
    if (t < HID)
        hfin[(size_t)b * 512 + t] = hls[0][HPERM(t)];
}

// ---------------------------------------------------------------------------
// Phase 3: out[b][o] = sum_k h[b][k] * Wfc[o][k] + bfc[o]  (fp32 out)
// 32 blocks x 16 o-slice, 256 threads; h staged in padded LDS.
// ---------------------------------------------------------------------------
#define P3_HS 520  // padded stride (f16); 1040B is 16B-aligned

__global__ __launch_bounds__(256, 2) void fc_kernel(
    const f16* __restrict__ hfin, const float* __restrict__ Wfc,
    const float* __restrict__ bfc, float* __restrict__ out)
{
    __shared__ __align__(16) f16 hs[BATCH * P3_HS];
    const int t = threadIdx.x;
    // stage h (coalesced 2B loads, scattered padded LDS writes — one-time)
    for (int i = 0; i < 64; i++) {
        int e = i * 256 + t;                 // 0..16383
        hs[(e >> 9) * P3_HS + (e & 511)] = hfin[e];
    }
    __syncthreads();

    const int bidx = t & 31;
    const int oi = t >> 5;                   // 0..7
    const int o0 = blockIdx.x * 16;
    const int oA = o0 + oi, oB = o0 + oi + 8;
    const float* wA = Wfc + (size_t)oA * 512;
    const float* wB = Wfc + (size_t)oB * 512;

    float sA = 0.f, sB = 0.f;
#pragma unroll 4
    for (int kb = 0; kb < 64; kb++) {
        f16x8 hv = *(const f16x8*)&hs[bidx * P3_HS + kb * 8];
        float4 wa0 = *(const float4*)(wA + kb * 8);
        float4 wa1 = *(const float4*)(wA + kb * 8 + 4);
        float4 wb0 = *(const float4*)(wB + kb * 8);
        float4 wb1 = *(const float4*)(wB + kb * 8 + 4);
        float h0 = (float)hv[0], h1 = (float)hv[1], h2 = (float)hv[2], h3 = (float)hv[3];
        float h4 = (float)hv[4], h5 = (float)hv[5], h6 = (float)hv[6], h7 = (float)hv[7];
        sA += wa0.x*h0 + wa0.y*h1 + wa0.z*h2 + wa0.w*h3 + wa1.x*h4 + wa1.y*h5 + wa1.z*h6 + wa1.w*h7;
        sB += wb0.x*h0 + wb0.y*h1 + wb0.z*h2 + wb0.w*h3 + wb1.x*h4 + wb1.y*h5 + wb1.z*h6 + wb1.w*h7;
    }
    out[(size_t)bidx * 512 + oA] = sA + bfc[oA];
    out[(size_t)bidx * 512 + oB] = sB + bfc[oB];
}

// ---------------------------------------------------------------------------
extern "C" void kernel_launch(void* const* d_in, const int* in_sizes, int n_in,
                              void* d_out, int out_size, void* d_ws, size_t ws_size,
                              hipStream_t stream) {
    const float* x    = (const float*)d_in[0];
    const float* Wxh  = (const float*)d_in[1];
    const float* bxh  = (const float*)d_in[2];
    const float* Whh  = (const float*)d_in[3];
    const float* bhh  = (const float*)d_in[4];
    const float* bh   = (const float*)d_in[5];
    const float* Wfc  = (const float*)d_in[6];
    const float* bfc  = (const float*)d_in[7];
    float* outp = (float*)d_out;

    f16* xp   = (f16*)d_ws;                                   // 64 MiB
    f16* hfin = (f16*)((char*)d_ws + (size_t)BATCH * SEQL * 512 * 2);

    xproj_kernel<<<(BATCH * SEQL) / 64, 256, 0, stream>>>(x, Wxh, bxh, bhh, bh, xp);
    rnn_kernel<<<BATCH, 1024, 0, stream>>>(Whh, xp, hfin);
    fc_kernel<<<32, 256, 0, stream>>>(hfin, Wfc, bfc, outp);
}

// Round 8
// 2684.976 us; speedup vs baseline: 4.6214x; 4.6214x over previous
//
#include <hip/hip_runtime.h>

typedef _Float16 f16;
typedef _Float16 f16x8 __attribute__((ext_vector_type(8)));
typedef float    f32x4 __attribute__((ext_vector_type(4)));

#define NSTEP 2048
#define HID   512
#define BATCH 32
#define SEQL  2048

// ---------------------------------------------------------------------------
// One-time W_xh f32 -> f16 conversion (512x512 = 256K elems, ~10 us).
// Removes the per-block f32->f16 B-staging cvt burden from xproj (the m33
// "VALU-bound staging" pattern: 262K cvt+pack per block x 1024 blocks).
// ---------------------------------------------------------------------------
__global__ __launch_bounds__(256, 4) void wcvt_kernel(
    const float* __restrict__ W, f16* __restrict__ Wf)
{
    int i = (blockIdx.x * 256 + threadIdx.x) * 8;
    float4 a0 = *(const float4*)(W + i);
    float4 a1 = *(const float4*)(W + i + 4);
    f16x8 h;
    h[0] = (f16)a0.x; h[1] = (f16)a0.y; h[2] = (f16)a0.z; h[3] = (f16)a0.w;
    h[4] = (f16)a1.x; h[5] = (f16)a1.y; h[6] = (f16)a1.z; h[7] = (f16)a1.w;
    *(f16x8*)&Wf[i] = h;
}

// ---------------------------------------------------------------------------
// Phase 1: xproj[m][n] = sum_k x[m][k] * Wxh[n][k] + (bxh+bhh+bh)[n], f16 out
// M=65536, N=512, K=512.  Block: 64 rows x 512 cols, 256 threads (4 waves).
// Two variants: _f16 (B staged as pure f16 copy from pre-converted Wxh) and
// the original f32-B fallback (used only if ws_size can't hold Wf16).
// ---------------------------------------------------------------------------
#define P1_AS 40   // padded lds stride (f16) to spread banks; 80B = 16B-aligned

__global__ __launch_bounds__(256, 2) void xproj_f16_kernel(
    const float* __restrict__ x, const f16* __restrict__ Wf16,
    const float* __restrict__ bxh, const float* __restrict__ bhh,
    const float* __restrict__ bh, f16* __restrict__ xp)
{
    __shared__ __align__(16) f16 As[64 * P1_AS];
    __shared__ __align__(16) f16 Bs[512 * P1_AS];

    const int t = threadIdx.x;
    const int wave = t >> 6, lane = t & 63;
    const size_t mbase = (size_t)blockIdx.x * 64;

    f32x4 acc[4][8];
#pragma unroll
    for (int i = 0; i < 4; i++)
#pragma unroll
        for (int j = 0; j < 8; j++) acc[i][j] = (f32x4){0.f, 0.f, 0.f, 0.f};

    const int r_st = t >> 2;          // 0..63
    const int koff = (t & 3) * 8;     // 0,8,16,24

    for (int k0 = 0; k0 < 512; k0 += 32) {
        __syncthreads();
        // stage A: 64 rows x 32 k (f32 -> f16; small: 2048 cvt/chunk/block)
        {
            const float* src = x + (mbase + r_st) * 512 + k0 + koff;
            float4 a0 = *(const float4*)src;
            float4 a1 = *(const float4*)(src + 4);
            f16x8 h;
            h[0] = (f16)a0.x; h[1] = (f16)a0.y; h[2] = (f16)a0.z; h[3] = (f16)a0.w;
            h[4] = (f16)a1.x; h[5] = (f16)a1.y; h[6] = (f16)a1.z; h[7] = (f16)a1.w;
            *(f16x8*)&As[r_st * P1_AS + koff] = h;
        }
        // stage B: pure f16x8 copy (no cvt) — the r8 change
#pragma unroll
        for (int i = 0; i < 8; i++) {
            int n = r_st + i * 64;
            *(f16x8*)&Bs[n * P1_AS + koff] =
                *(const f16x8*)(Wf16 + (size_t)n * 512 + k0 + koff);
        }
        __syncthreads();

        // A frags: row = rt*16 + (lane&15), k = (lane>>4)*8 + j
        f16x8 af[4];
#pragma unroll
        for (int rt = 0; rt < 4; rt++)
            af[rt] = *(const f16x8*)&As[(rt * 16 + (lane & 15)) * P1_AS + (lane >> 4) * 8];
#pragma unroll
        for (int ct = 0; ct < 8; ct++) {
            f16x8 bf = *(const f16x8*)&Bs[((wave * 8 + ct) * 16 + (lane & 15)) * P1_AS + (lane >> 4) * 8];
#pragma unroll
            for (int rt = 0; rt < 4; rt++)
                acc[rt][ct] = __builtin_amdgcn_mfma_f32_16x16x32_f16(af[rt], bf, acc[rt][ct], 0, 0, 0);
        }
    }

    // epilogue: D col = lane&15, row = (lane>>4)*4 + r
#pragma unroll
    for (int ct = 0; ct < 8; ct++) {
        int n = wave * 128 + ct * 16 + (lane & 15);
        float bias = bxh[n] + bhh[n] + bh[n];
#pragma unroll
        for (int rt = 0; rt < 4; rt++) {
#pragma unroll
            for (int r = 0; r < 4; r++) {
                size_t m = mbase + rt * 16 + (lane >> 4) * 4 + r;
                xp[m * 512 + n] = (f16)(acc[rt][ct][r] + bias);
            }
        }
    }
}

__global__ __launch_bounds__(256, 2) void xproj_kernel(
    const float* __restrict__ x, const float* __restrict__ Wxh,
    const float* __restrict__ bxh, const float* __restrict__ bhh,
    const float* __restrict__ bh, f16* __restrict__ xp)
{
    __shared__ __align__(16) f16 As[64 * P1_AS];
    __shared__ __align__(16) f16 Bs[512 * P1_AS];

    const int t = threadIdx.x;
    const int wave = t >> 6, lane = t & 63;
    const size_t mbase = (size_t)blockIdx.x * 64;

    f32x4 acc[4][8];
#pragma unroll
    for (int i = 0; i < 4; i++)
#pragma unroll
        for (int j = 0; j < 8; j++) acc[i][j] = (f32x4){0.f, 0.f, 0.f, 0.f};

    const int r_st = t >> 2;
    const int koff = (t & 3) * 8;

    for (int k0 = 0; k0 < 512; k0 += 32) {
        __syncthreads();
        {
            const float* src = x + (mbase + r_st) * 512 + k0 + koff;
            float4 a0 = *(const float4*)src;
            float4 a1 = *(const float4*)(src + 4);
            f16x8 h;
            h[0] = (f16)a0.x; h[1] = (f16)a0.y; h[2] = (f16)a0.z; h[3] = (f16)a0.w;
            h[4] = (f16)a1.x; h[5] = (f16)a1.y; h[6] = (f16)a1.z; h[7] = (f16)a1.w;
            *(f16x8*)&As[r_st * P1_AS + koff] = h;
        }
#pragma unroll
        for (int i = 0; i < 8; i++) {
            int n = r_st + i * 64;
            const float* src = Wxh + (size_t)n * 512 + k0 + koff;
            float4 b0 = *(const float4*)src;
            float4 b1 = *(const float4*)(src + 4);
            f16x8 h;
            h[0] = (f16)b0.x; h[1] = (f16)b0.y; h[2] = (f16)b0.z; h[3] = (f16)b0.w;
            h[4] = (f16)b1.x; h[5] = (f16)b1.y; h[6] = (f16)b1.z; h[7] = (f16)b1.w;
            *(f16x8*)&Bs[n * P1_AS + koff] = h;
        }
        __syncthreads();

        f16x8 af[4];
#pragma unroll
        for (int rt = 0; rt < 4; rt++)
            af[rt] = *(const f16x8*)&As[(rt * 16 + (lane & 15)) * P1_AS + (lane >> 4) * 8];
#pragma unroll
        for (int ct = 0; ct < 8; ct++) {
            f16x8 bf = *(const f16x8*)&Bs[((wave * 8 + ct) * 16 + (lane & 15)) * P1_AS + (lane >> 4) * 8];
#pragma unroll
            for (int rt = 0; rt < 4; rt++)
                acc[rt][ct] = __builtin_amdgcn_mfma_f32_16x16x32_f16(af[rt], bf, acc[rt][ct], 0, 0, 0);
        }
    }

#pragma unroll
    for (int ct = 0; ct < 8; ct++) {
        int n = wave * 128 + ct * 16 + (lane & 15);
        float bias = bxh[n] + bhh[n] + bh[n];
#pragma unroll
        for (int rt = 0; rt < 4; rt++) {
#pragma unroll
            for (int r = 0; r < 4; r++) {
                size_t m = mbase + rt * 16 + (lane >> 4) * 4 + r;
                xp[m * 512 + n] = (f16)(acc[rt][ct][r] + bias);
            }
        }
    }
}

// ---------------------------------------------------------------------------
// Phase 2: recurrence.  EXACT r0 restoration (measured 2447 us — best).
// 1 block (512 thr, 8 waves) per batch, 32 blocks.  W_hh f16 B-fragment
// layout: 3 N-tiles/wave in regs (192, AGPR-eligible), 1 N-tile/wave in LDS
// (128 KiB).  h double-buffered in LDS; 1 barrier/step; dist-1 float xp
// prefetch.  Structural note (r3/r7 analysis): this is ~87% of the MFMA-issue
// bound of the replicate-W paradigm (512 mfma/step/CU = 2483 cyc); W_hh
// (512 KB) = the CU's whole VGPR file, so VALU offload can't hold weights
// (r5-r7 all spilled).  Going below this needs cross-CU column-split + per-
// step device-scope sync — not attempted here.
// ---------------------------------------------------------------------------
#define P2_LDS_BYTES (2 * HID * 2 + 8 * 16 * 64 * 16)  // h bufs + ldsB = 133120

__global__ __launch_bounds__(512, 2) void rnn_kernel(
    const float* __restrict__ Whh, const f16* __restrict__ xp,
    f16* __restrict__ hfin)
{
    extern __shared__ __align__(16) char smem[];
    f16* hbuf0 = (f16*)smem;                 // 512
    f16* hbuf1 = hbuf0 + HID;                // 512
    f16* ldsB  = hbuf1 + HID;                // [(wave*16+kf)*64 + lane]*8 f16

    const int t = threadIdx.x;
    const int wave = t >> 6, lane = t & 63;
    const int b = blockIdx.x;

    const int c_in = lane & 15;              // fragment column
    const int k8   = (lane >> 4) * 8;        // fragment k base

    // ---- load W_hh fragments (one-time): tile nt = wave*4 + r ----
    f16x8 wreg[48];                          // 3 tiles x 16 kf -> 192 VGPRs
#pragma unroll
    for (int r = 0; r < 3; r++) {
        const float* wrow = Whh + (size_t)((wave * 4 + r) * 16 + c_in) * 512;
#pragma unroll
        for (int kf = 0; kf < 16; kf++) {
            float4 w0 = *(const float4*)(wrow + kf * 32 + k8);
            float4 w1 = *(const float4*)(wrow + kf * 32 + k8 + 4);
            f16x8 h;
            h[0] = (f16)w0.x; h[1] = (f16)w0.y; h[2] = (f16)w0.z; h[3] = (f16)w0.w;
            h[4] = (f16)w1.x; h[5] = (f16)w1.y; h[6] = (f16)w1.z; h[7] = (f16)w1.w;
            wreg[r * 16 + kf] = h;
        }
    }
    {   // 4th tile -> LDS in fragment order
        const float* wrow = Whh + (size_t)((wave * 4 + 3) * 16 + c_in) * 512;
#pragma unroll
        for (int kf = 0; kf < 16; kf++) {
            float4 w0 = *(const float4*)(wrow + kf * 32 + k8);
            float4 w1 = *(const float4*)(wrow + kf * 32 + k8 + 4);
            f16x8 h;
            h[0] = (f16)w0.x; h[1] = (f16)w0.y; h[2] = (f16)w0.z; h[3] = (f16)w0.w;
            h[4] = (f16)w1.x; h[5] = (f16)w1.y; h[6] = (f16)w1.z; h[7] = (f16)w1.w;
            *(f16x8*)&ldsB[(size_t)wave * 8192 + kf * 512 + lane * 8] = h;
        }
    }
    hbuf0[t & (HID - 1)] = (f16)0.f;         // h0 = 0 (512 threads cover 512)
    __syncthreads();

    const f16* xprow = xp + (size_t)b * SEQL * 512 + wave * 64 + lane;
    const int ldsb_base = wave * 8192 + lane * 8;

    float xv = (float)xprow[0];              // xp for step 0
    for (int s = 0; s < NSTEP; s++) {
        const f16* cur = (s & 1) ? hbuf1 : hbuf0;
        f16*       nxt = (s & 1) ? hbuf0 : hbuf1;
        // prefetch next step's xp (off critical path)
        int sn = (s + 1 < NSTEP) ? s + 1 : s;
        float xv_next = (float)xprow[(size_t)sn * 512];

        f32x4 a0 = (f32x4){0.f,0.f,0.f,0.f}, a1 = a0, a2 = a0, a3 = a0;
#pragma unroll
        for (int kf = 0; kf < 16; kf++) {
            // A broadcast frag: every "row" of A is h -> addr indep of lane&15
            f16x8 av = *(const f16x8*)&cur[kf * 32 + k8];
            a0 = __builtin_amdgcn_mfma_f32_16x16x32_f16(av, wreg[kf],      a0, 0, 0, 0);
            a1 = __builtin_amdgcn_mfma_f32_16x16x32_f16(av, wreg[16 + kf], a1, 0, 0, 0);
            a2 = __builtin_amdgcn_mfma_f32_16x16x32_f16(av, wreg[32 + kf], a2, 0, 0, 0);
            f16x8 bl = *(const f16x8*)&ldsB[ldsb_base + kf * 512];
            a3 = __builtin_amdgcn_mfma_f32_16x16x32_f16(av, bl, a3, 0, 0, 0);
        }
        // lane l owns h_new[wave*64 + l]: tile = l>>4, col = l&15, any row (reg 0)
        int r = lane >> 4;
        float v = (r == 0) ? a0[0] : (r == 1) ? a1[0] : (r == 2) ? a2[0] : a3[0];
        v += xv;
        // tanh(v) = 1 - 2/(exp(2v)+1)   (saturates correctly, no NaN)
        float e = __expf(2.f * v);
        v = 1.f - 2.f / (e + 1.f);
        nxt[wave * 64 + lane] = (f16)v;
        xv = xv_next;
        __syncthreads();
    }
    // NSTEP even -> final h sits in hbuf0
    hfin[(size_t)b * 512 + t] = hbuf0[t & (HID - 1)];
}

// ---------------------------------------------------------------------------
// Phase 3: out[b][o] = sum_k h[b][k] * Wfc[o][k] + bfc[o]  (fp32 out)
// 32 blocks x 16 o-slice, 256 threads; h staged in padded LDS.
// ---------------------------------------------------------------------------
#define P3_HS 520  // padded stride (f16); 1040B is 16B-aligned

__global__ __launch_bounds__(256, 2) void fc_kernel(
    const f16* __restrict__ hfin, const float* __restrict__ Wfc,
    const float* __restrict__ bfc, float* __restrict__ out)
{
    __shared__ __align__(16) f16 hs[BATCH * P3_HS];
    const int t = threadIdx.x;
    // stage h (coalesced 2B loads, scattered padded LDS writes — one-time)
    for (int i = 0; i < 64; i++) {
        int e = i * 256 + t;                 // 0..16383
        hs[(e >> 9) * P3_HS + (e & 511)] = hfin[e];
    }
    __syncthreads();

    const int bidx = t & 31;
    const int oi = t >> 5;                   // 0..7
    const int o0 = blockIdx.x * 16;
    const int oA = o0 + oi, oB = o0 + oi + 8;
    const float* wA = Wfc + (size_t)oA * 512;
    const float* wB = Wfc + (size_t)oB * 512;

    float sA = 0.f, sB = 0.f;
#pragma unroll 4
    for (int kb = 0; kb < 64; kb++) {
        f16x8 hv = *(const f16x8*)&hs[bidx * P3_HS + kb * 8];
        float4 wa0 = *(const float4*)(wA + kb * 8);
        float4 wa1 = *(const float4*)(wA + kb * 8 + 4);
        float4 wb0 = *(const float4*)(wB + kb * 8);
        float4 wb1 = *(const float4*)(wB + kb * 8 + 4);
        float h0 = (float)hv[0], h1 = (float)hv[1], h2 = (float)hv[2], h3 = (float)hv[3];
        float h4 = (float)hv[4], h5 = (float)hv[5], h6 = (float)hv[6], h7 = (float)hv[7];
        sA += wa0.x*h0 + wa0.y*h1 + wa0.z*h2 + wa0.w*h3 + wa1.x*h4 + wa1.y*h5 + wa1.z*h6 + wa1.w*h7;
        sB += wb0.x*h0 + wb0.y*h1 + wb0.z*h2 + wb0.w*h3 + wb1.x*h4 + wb1.y*h5 + wb1.z*h6 + wb1.w*h7;
    }
    out[(size_t)bidx * 512 + oA] = sA + bfc[oA];
    out[(size_t)bidx * 512 + oB] = sB + bfc[oB];
}

// ---------------------------------------------------------------------------
extern "C" void kernel_launch(void* const* d_in, const int* in_sizes, int n_in,
                              void* d_out, int out_size, void* d_ws, size_t ws_size,
                              hipStream_t stream) {
    const float* x    = (const float*)d_in[0];
    const float* Wxh  = (const float*)d_in[1];
    const float* bxh  = (const float*)d_in[2];
    const float* Whh  = (const float*)d_in[3];
    const float* bhh  = (const float*)d_in[4];
    const float* bh   = (const float*)d_in[5];
    const float* Wfc  = (const float*)d_in[6];
    const float* bfc  = (const float*)d_in[7];
    float* outp = (float*)d_out;

    const size_t xp_bytes   = (size_t)BATCH * SEQL * 512 * 2;   // 64 MiB
    const size_t hfin_bytes = (size_t)BATCH * 512 * 2;          // 32 KiB
    f16* xp   = (f16*)d_ws;
    f16* hfin = (f16*)((char*)d_ws + xp_bytes);
    f16* wf16 = (f16*)((char*)d_ws + xp_bytes + hfin_bytes);

    // allow 130 KiB dynamic LDS for the rnn kernel (idempotent, capture-safe)
    hipFuncSetAttribute((const void*)rnn_kernel,
                        hipFuncAttributeMaxDynamicSharedMemorySize, 160 * 1024);

    if (ws_size >= xp_bytes + hfin_bytes + (size_t)512 * 512 * 2) {
        // fast path: one-time Wxh f32->f16, then copy-staged GEMM
        wcvt_kernel<<<128, 256, 0, stream>>>(Wxh, wf16);
        xproj_f16_kernel<<<(BATCH * SEQL) / 64, 256, 0, stream>>>(
            x, wf16, bxh, bhh, bh, xp);
    } else {
        xproj_kernel<<<(BATCH * SEQL) / 64, 256, 0, stream>>>(
            x, Wxh, bxh, bhh, bh, xp);
    }
    rnn_kernel<<<BATCH, 512, P2_LDS_BYTES, stream>>>(Whh, xp, hfin);
    fc_kernel<<<32, 256, 0, stream>>>(hfin, Wfc, bfc, outp);
}